// Round 8
// baseline (672.740 us; speedup 1.0000x reference)
//
#include <hip/hip_runtime.h>
#include <hip/hip_bf16.h>
#include <stdint.h>

#define HID 1024
#define FFD 4096
#define FFH 2048          // FF half
#define NE  8
#define NTOK 4096
#define BM 128
#define BN 128
#define BK 32
#define RBCAP 72
#define ROWCAP (RBCAP*BM)   // 9216

typedef __attribute__((ext_vector_type(8))) short short8;
typedef __attribute__((ext_vector_type(4))) float f32x4;

__device__ __forceinline__ unsigned short f2bf(float f){
  union { float f; unsigned u; } v; v.f = f;
  return (unsigned short)((v.u + 0x7FFFu + ((v.u >> 16) & 1u)) >> 16);  // RNE
}

__device__ __forceinline__ float gelu_f(float x){
  float u = 0.7978845608028654f * (x + 0.044715f * x * x * x);
  return 0.5f * x * (1.0f + tanhf(u));
}

__device__ __forceinline__ void gload_lds16(const void* g, void* l){
  __builtin_amdgcn_global_load_lds((const __attribute__((address_space(1))) void*)g,
                                   (__attribute__((address_space(3))) void*)l,
                                   16, 0, 0);
}

// ---------------- router: logits (f64 accum), softmax fp32, top-2. NO atomics. ------------
__global__ __launch_bounds__(256) void router_k(
    const float* __restrict__ x, const float* __restrict__ Wr,
    float* __restrict__ out_logits, float* __restrict__ out_sel,
    int* __restrict__ tok_sel, float* __restrict__ tok_w)
{
  const int lane = threadIdx.x & 63;
  const int t = (blockIdx.x << 2) + (threadIdx.x >> 6);
  const float* xr = x + (size_t)t * HID;
  double acc[NE];
  #pragma unroll
  for (int e = 0; e < NE; ++e) acc[e] = 0.0;
  #pragma unroll
  for (int i = 0; i < 4; ++i) {
    const int h0 = i * 256 + lane * 4;
    float4 xv = *(const float4*)(xr + h0);
    #pragma unroll
    for (int r = 0; r < 4; ++r) {
      float xs = (&xv.x)[r];
      float4 w0 = *(const float4*)(Wr + (size_t)(h0 + r) * NE);
      float4 w1 = *(const float4*)(Wr + (size_t)(h0 + r) * NE + 4);
      acc[0] += (double)xs * w0.x;  acc[1] += (double)xs * w0.y;
      acc[2] += (double)xs * w0.z;  acc[3] += (double)xs * w0.w;
      acc[4] += (double)xs * w1.x;  acc[5] += (double)xs * w1.y;
      acc[6] += (double)xs * w1.z;  acc[7] += (double)xs * w1.w;
    }
  }
  #pragma unroll
  for (int off = 32; off > 0; off >>= 1) {
    #pragma unroll
    for (int e = 0; e < NE; ++e) acc[e] += __shfl_down(acc[e], off);
  }
  if (lane == 0) {
    float lg[NE], p[NE];
    float mx = -3.4e38f;
    #pragma unroll
    for (int e = 0; e < NE; ++e) { lg[e] = (float)acc[e]; mx = fmaxf(mx, lg[e]); }
    float s = 0.f;
    #pragma unroll
    for (int e = 0; e < NE; ++e) { p[e] = expf(lg[e] - mx); s += p[e]; }
    float inv = 1.0f / s;
    #pragma unroll
    for (int e = 0; e < NE; ++e) p[e] *= inv;
    #pragma unroll
    for (int e = 0; e < NE; ++e) out_logits[(size_t)t * NE + e] = lg[e];
    int e0 = 0;
    #pragma unroll
    for (int e = 1; e < NE; ++e) if (p[e] > p[e0]) e0 = e;      // tie -> lower idx
    int e1 = (e0 == 0) ? 1 : 0;
    #pragma unroll
    for (int e = 0; e < NE; ++e) if (e != e0 && p[e] > p[e1]) e1 = e;
    out_sel[(size_t)t * 2 + 0] = (float)e0;
    out_sel[(size_t)t * 2 + 1] = (float)e1;
    tok_sel[t * 2 + 0] = e0;  tok_sel[t * 2 + 1] = e1;
    tok_w[t * 2 + 0] = p[e0]; tok_w[t * 2 + 1] = p[e1];
  }
}

// ------- partition: histogram + scan + rowblock table + pair scatter, one block, no atomics
__global__ __launch_bounds__(1024) void part_k(
    const int* __restrict__ tok_sel, const float* __restrict__ tok_w,
    int* __restrict__ pair_tok, float* __restrict__ pair_w,
    int* __restrict__ rb2e, int* __restrict__ rb2row, int* __restrict__ nrb)
{
  __shared__ unsigned sc[1024][NE];
  __shared__ unsigned shOffs[NE];
  const int tid = threadIdx.x;
  int pe[8];
  unsigned cnt[NE] = {0,0,0,0,0,0,0,0};
  #pragma unroll
  for (int j = 0; j < 8; ++j) {
    int e = tok_sel[tid * 8 + j];
    pe[j] = e;
    #pragma unroll
    for (int k = 0; k < NE; ++k) cnt[k] += (e == k) ? 1u : 0u;   // static indexing
  }
  #pragma unroll
  for (int k = 0; k < NE; ++k) sc[tid][k] = cnt[k];
  __syncthreads();
  // inclusive scan across 1024 threads
  for (int off = 1; off < 1024; off <<= 1) {
    unsigned v[NE];
    const bool act = (tid >= off);
    if (act) {
      #pragma unroll
      for (int k = 0; k < NE; ++k) v[k] = sc[tid - off][k];
    }
    __syncthreads();
    if (act) {
      #pragma unroll
      for (int k = 0; k < NE; ++k) sc[tid][k] += v[k];
    }
    __syncthreads();
  }
  if (tid == 0) {
    unsigned row = 0; int rb = 0;
    #pragma unroll
    for (int e = 0; e < NE; ++e) {
      shOffs[e] = row;
      int nb = (int)((sc[1023][e] + 127u) >> 7);
      for (int b = 0; b < nb; ++b) { rb2e[rb] = e; rb2row[rb] = (int)row + b * BM; ++rb; }
      row += (unsigned)nb << 7;
    }
    nrb[0] = rb;
  }
  __syncthreads();
  // deterministic scatter (pair order = q order within each expert)
  #pragma unroll
  for (int j = 0; j < 8; ++j) {
    int e = pe[j];
    int rank = 0;
    #pragma unroll
    for (int j2 = 0; j2 < 8; ++j2) if (j2 < j) rank += (pe[j2] == e) ? 1 : 0;
    unsigned prev = (tid > 0) ? sc[tid - 1][e] : 0u;
    int p = (int)(shOffs[e] + prev) + rank;
    int q = tid * 8 + j;
    pair_tok[p] = q >> 1;
    pair_w[p] = tok_w[q];
  }
}

// ---------------- gather selected rows of x -> bf16 ----------------
__global__ __launch_bounds__(256) void gather_k(
    const float* __restrict__ x, const int* __restrict__ pair_tok, unsigned short* __restrict__ Xg)
{
  const int lane = threadIdx.x & 63;
  const int p = (blockIdx.x << 2) + (threadIdx.x >> 6);
  int t = pair_tok[p];
  if (t < 0) return;                       // padding row: never consumed
  const float* src = x + (size_t)t * HID;
  unsigned short* dst = Xg + (size_t)p * HID;
  #pragma unroll
  for (int i = 0; i < 4; ++i) {
    float4 v = *(const float4*)(src + lane * 4 + i * 256);
    unsigned a = (unsigned)f2bf(v.x) | ((unsigned)f2bf(v.y) << 16);
    unsigned b = (unsigned)f2bf(v.z) | ((unsigned)f2bf(v.w) << 16);
    *(uint2*)(dst + lane * 4 + i * 256) = make_uint2(a, b);
  }
}

// ------- weight transpose+convert: out[e][n][k] = bf16(in_e[k*ld_in + n]) -------
// tile 128k x 64n; in-register 4x4 transpose; uint4 global writes (16B).
template<int KSUB, int NSUB>
__global__ __launch_bounds__(256) void wtrans_k(const float* __restrict__ in,
                                               unsigned short* __restrict__ out,
                                               int ld_in, size_t in_estride)
{
  const int tilesN = NSUB / 64;
  const int tk = blockIdx.x / tilesN, tn = blockIdx.x % tilesN;
  const int k0 = tk * 128, n0 = tn * 64;
  const float* ine = in + (size_t)blockIdx.y * in_estride;
  unsigned short* oute = out + (size_t)blockIdx.y * ((size_t)KSUB * NSUB);
  __shared__ unsigned short lds[64][136];   // [n][k], 272B row (16-aligned)
  const int t = threadIdx.x;
  #pragma unroll
  for (int i = 0; i < 2; ++i) {
    int idx = i * 256 + t;              // [0,512)
    int c4  = (idx & 15) * 4;           // n within tile
    int kr4 = (idx >> 4) * 4;           // k row group, [0,128) step 4
    float4 v[4];
    #pragma unroll
    for (int jj = 0; jj < 4; ++jj)
      v[jj] = *(const float4*)(ine + (size_t)(k0 + kr4 + jj) * ld_in + n0 + c4);
    #pragma unroll
    for (int j = 0; j < 4; ++j) {
      uint2 w;
      w.x = (unsigned)f2bf((&v[0].x)[j]) | ((unsigned)f2bf((&v[1].x)[j]) << 16);
      w.y = (unsigned)f2bf((&v[2].x)[j]) | ((unsigned)f2bf((&v[3].x)[j]) << 16);
      *(uint2*)&lds[c4 + j][kr4] = w;
    }
  }
  __syncthreads();
  #pragma unroll
  for (int i = 0; i < 4; ++i) {
    int idx = i * 256 + t;              // [0,1024)
    int nrow = idx >> 4;                // [0,64)
    int kc8  = (idx & 15) * 8;          // [0,128) step 8
    uint4 w = *(const uint4*)&lds[nrow][kc8];
    *(uint4*)(oute + (size_t)(n0 + nrow) * KSUB + k0 + kc8) = w;
  }
}

// ---------------- expert-tiled GEMM: dbuf stage-ahead + bijective XCD swizzle ----------
// A: bf16 [rows][KDIM].  Bt: bf16 [NE][NDIM][KDIM] (k-contiguous).  1-D grid (XT*RBCAP).
template<int KDIM, int NDIM, int XT, int BIAS_STRIDE, bool DOGELU, bool ADD_BIAS>
__global__ __launch_bounds__(256) void gemm_k(
    const unsigned short* __restrict__ A, const unsigned short* __restrict__ Bt,
    const float* __restrict__ bias,
    const int* __restrict__ nrb, const int* __restrict__ rb2e, const int* __restrict__ rb2row,
    unsigned short* __restrict__ Hout,
    const int* __restrict__ pair_tok, const float* __restrict__ pair_w,
    float* __restrict__ out)
{
  // bijective XCD swizzle: each XCD gets a contiguous chunk of (rb-major, bn-fastest) space
  const int nwg = XT * RBCAP;                   // % 8 == 0
  const int bid = (int)blockIdx.x;
  const int swz = (bid & 7) * (nwg >> 3) + (bid >> 3);
  const int bx  = swz % XT;
  const int by  = swz / XT;
  if (by >= nrb[0]) return;
  const int e    = rb2e[by];
  const int row0 = rb2row[by];
  const int bn   = bx * BN;

  __shared__ __align__(16) unsigned short As[2][BM * BK];   // [row][k], 8 KB each
  __shared__ __align__(16) unsigned short Bs[2][BN * BK];   // [n][k]

  const int tid = threadIdx.x;
  const int lane = tid & 63, wave = tid >> 6;
  const int wm = wave >> 1, wn = wave & 1;
  const unsigned short* Be = Bt + (size_t)e * KDIM * NDIM;

  f32x4 acc[4][4];
  #pragma unroll
  for (int m = 0; m < 4; ++m)
    #pragma unroll
    for (int n = 0; n < 4; ++n) acc[m][n] = f32x4{0.f, 0.f, 0.f, 0.f};

  const int mrow0 = tid >> 2;               // staging row for r=0 chunk
  const int koff0 = (tid & 3) * 8;
  // wave-uniform LDS dest offsets (HW adds lane*16B)
  const int ldsoff = wave * 64 * 8;         // u16 units

  auto stage = [&](int buf, int kt) {
    #pragma unroll
    for (int r = 0; r < 2; ++r) {
      int mrow = mrow0 + r * 64;
      gload_lds16((const void*)(A + (size_t)(row0 + mrow) * KDIM + kt + koff0),
                  (void*)(&As[buf][0] + (size_t)(r * 256 * 8) + ldsoff));
      gload_lds16((const void*)(Be + (size_t)(bn + mrow) * KDIM + kt + koff0),
                  (void*)(&Bs[buf][0] + (size_t)(r * 256 * 8) + ldsoff));
    }
  };

  constexpr int NIT = KDIM / BK;
  stage(0, 0);
  __syncthreads();                          // drains vmcnt -> buf0 ready

  const int kc = lane >> 4, rsel0 = lane & 15;
  for (int it = 0; it < NIT; ++it) {
    const int cur = it & 1;
    if (it + 1 < NIT) stage(cur ^ 1, (it + 1) * BK);   // loads fly under compute
    const unsigned short* Ac = &As[cur][0];
    const unsigned short* Bc = &Bs[cur][0];
    short8 af[4], bfr[4];
    #pragma unroll
    for (int m = 0; m < 4; ++m)
      af[m] = *(const short8*)&Ac[(wm * 64 + m * 16 + rsel0) * BK + kc * 8];
    #pragma unroll
    for (int n = 0; n < 4; ++n)
      bfr[n] = *(const short8*)&Bc[(wn * 64 + n * 16 + rsel0) * BK + kc * 8];
    #pragma unroll
    for (int m = 0; m < 4; ++m)
      #pragma unroll
      for (int n = 0; n < 4; ++n)
        acc[m][n] = __builtin_amdgcn_mfma_f32_16x16x32_bf16(af[m], bfr[n], acc[m][n], 0, 0, 0);
    __syncthreads();                        // waits stage(next) + everyone's reads of cur
  }

  // epilogue. C/D map: col = lane&15, row = (lane>>4)*4 + i
  const int rsel = lane & 15, quad = lane >> 4;
  float bvv[4];
  #pragma unroll
  for (int n = 0; n < 4; ++n)
    bvv[n] = ADD_BIAS ? bias[(size_t)e * BIAS_STRIDE + bn + wn * 64 + n * 16 + rsel] : 0.f;

  if constexpr (DOGELU) {
    #pragma unroll
    for (int m = 0; m < 4; ++m) {
      int r0 = row0 + wm * 64 + m * 16 + quad * 4;
      #pragma unroll
      for (int n = 0; n < 4; ++n) {
        int col = bn + wn * 64 + n * 16 + rsel;
        unsigned short* hp = Hout + (size_t)r0 * NDIM + col;
        #pragma unroll
        for (int i = 0; i < 4; ++i) {
          float v = acc[m][n][i] + bvv[n];
          hp[(size_t)i * NDIM] = f2bf(gelu_f(v));
        }
      }
    }
  } else {
    #pragma unroll
    for (int m = 0; m < 4; ++m) {
      #pragma unroll
      for (int i = 0; i < 4; ++i) {
        int p = row0 + wm * 64 + m * 16 + quad * 4 + i;
        int t = pair_tok[p];
        if (t < 0) continue;                    // padding row
        float w = pair_w[p];
        float* op = out + (size_t)t * HID;
        #pragma unroll
        for (int n = 0; n < 4; ++n) {
          int col = bn + wn * 64 + n * 16 + rsel;
          atomicAdd(op + col, w * (acc[m][n][i] + bvv[n]));
        }
      }
    }
  }
}

// ---------------- launch ----------------
extern "C" void kernel_launch(void* const* d_in, const int* in_sizes, int n_in,
                              void* d_out, int out_size, void* d_ws, size_t ws_size,
                              hipStream_t stream)
{
  const float* x  = (const float*)d_in[0];
  const float* Wr = (const float*)d_in[1];
  const float* W1 = (const float*)d_in[2];
  const float* b1 = (const float*)d_in[3];
  const float* W2 = (const float*)d_in[4];
  const float* b2 = (const float*)d_in[5];

  float* out        = (float*)d_out;                 // 4096*1024
  float* out_logits = out + (size_t)NTOK * HID;      // 4096*8
  float* out_sel    = out_logits + (size_t)NTOK * NE;// 4096*2 (as floats)

  char* ws = (char*)d_ws;
  int*   nrb      = (int*)(ws + 128);      // 1
  int*   rb2e     = (int*)(ws + 256);      // 128
  int*   rb2row   = (int*)(ws + 768);      // 128
  int*   tok_sel  = (int*)(ws + 1280);     // 4096*2
  float* tok_w    = (float*)(ws + 34048);  // 4096*2
  int*   pair_tok = (int*)(ws + 66816);    // 9216
  float* pair_w   = (float*)(ws + 103680); // 9216
  unsigned short* Xg  = (unsigned short*)(ws + 140800);    // ROWCAP*1024 bf16 (18.9 MB)
  unsigned short* Hh  = (unsigned short*)(ws + 19015168);  // ROWCAP*2048 bf16 (37.7 MB)
  unsigned short* Wth = (unsigned short*)(ws + 56763904);  // 8*2048*1024 bf16 (33.5 MB, reused)
  // peak ws usage: 90,318,336 B = 90.3 MB (< 94.5 MB proven in R1)

  hipMemsetAsync(pair_tok, 0xFF, (size_t)ROWCAP * 4, stream);  // -1 = padding
  hipMemsetAsync(d_out, 0, (size_t)out_size * 4, stream);

  router_k<<<NTOK / 4, 256, 0, stream>>>(x, Wr, out_logits, out_sel, tok_sel, tok_w);
  part_k<<<1, 1024, 0, stream>>>(tok_sel, tok_w, pair_tok, pair_w, rb2e, rb2row, nrb);
  gather_k<<<ROWCAP / 4, 256, 0, stream>>>(x, pair_tok, Xg);

  for (int h = 0; h < 2; ++h) {
    // W1 half: fp32 [H][FF] cols [h*2048, +2048) -> bf16 [E][2048][1024]
    dim3 gt1((HID / 128) * (FFH / 64), NE);
    wtrans_k<HID, FFH><<<gt1, 256, 0, stream>>>(
        W1 + (size_t)h * FFH, Wth, FFD, (size_t)HID * FFD);
    // GEMM1 half: Hh = gelu(Xg @ W1h + b1h);  grid = 16 x-tiles * 72 rb = 1152
    gemm_k<HID, FFH, FFH / BN, FFD, true, true><<<(FFH / BN) * RBCAP, 256, 0, stream>>>(
        Xg, Wth, b1 + (size_t)h * FFH, nrb, rb2e, rb2row, Hh, nullptr, nullptr, nullptr);
    // W2 half: fp32 rows [h*2048, +2048) of [FF][H] -> bf16 [E][1024][2048]
    dim3 gt2((FFH / 128) * (HID / 64), NE);
    wtrans_k<FFH, HID><<<gt2, 256, 0, stream>>>(
        W2 + (size_t)h * FFH * HID, Wth, HID, (size_t)FFD * HID);
    // GEMM2 half: out[tok] += w * (Hh @ W2h) (+ b2 on first pass only); grid = 8*72 = 576
    if (h == 0)
      gemm_k<FFH, HID, HID / BN, HID, false, true><<<(HID / BN) * RBCAP, 256, 0, stream>>>(
          Hh, Wth, b2, nrb, rb2e, rb2row, nullptr, pair_tok, pair_w, out);
    else
      gemm_k<FFH, HID, HID / BN, HID, false, false><<<(HID / BN) * RBCAP, 256, 0, stream>>>(
          Hh, Wth, b2, nrb, rb2e, rb2row, nullptr, pair_tok, pair_w, out);
  }
}